// Round 1
// baseline (512.258 us; speedup 1.0000x reference)
//
#include <hip/hip_runtime.h>
#include <hip/hip_bf16.h>

// Problem constants (match reference)
#define NN 50000
#define NE 800000
#define HID 128
#define NG 512
#define BN_EPS 1e-5f

// ---------------------------------------------------------------------------
// CSR build: histogram -> exclusive scan -> fill
// ---------------------------------------------------------------------------
__global__ __launch_bounds__(256) void hist_kernel(const int* __restrict__ ei,
                                                   int E, int* __restrict__ deg) {
    int e = blockIdx.x * 256 + threadIdx.x;
    if (e >= E) return;
    int dst = ei[E + e];
    atomicAdd(&deg[dst], 1);
}

__global__ __launch_bounds__(256) void scan1_kernel(const int* __restrict__ deg,
                                                    int* __restrict__ row_start,
                                                    int* __restrict__ bsums, int n) {
    __shared__ int s[256];
    int i = blockIdx.x * 256 + threadIdx.x;
    int v = (i < n) ? deg[i] : 0;
    s[threadIdx.x] = v;
    __syncthreads();
    for (int off = 1; off < 256; off <<= 1) {
        int t = (threadIdx.x >= off) ? s[threadIdx.x - off] : 0;
        __syncthreads();
        s[threadIdx.x] += t;
        __syncthreads();
    }
    if (i < n) row_start[i] = s[threadIdx.x] - v;  // exclusive
    if (threadIdx.x == 255) bsums[blockIdx.x] = s[255];
}

__global__ __launch_bounds__(256) void scan2_kernel(int* __restrict__ bsums, int nb) {
    __shared__ int s[256];
    int v = (threadIdx.x < nb) ? bsums[threadIdx.x] : 0;
    s[threadIdx.x] = v;
    __syncthreads();
    for (int off = 1; off < 256; off <<= 1) {
        int t = (threadIdx.x >= off) ? s[threadIdx.x - off] : 0;
        __syncthreads();
        s[threadIdx.x] += t;
        __syncthreads();
    }
    if (threadIdx.x < nb) bsums[threadIdx.x] = s[threadIdx.x] - v;  // exclusive
}

__global__ __launch_bounds__(256) void scan3_kernel(int* __restrict__ row_start,
                                                    const int* __restrict__ bsums, int n) {
    int i = blockIdx.x * 256 + threadIdx.x;
    if (i < n) row_start[i] += bsums[blockIdx.x];
}

__global__ __launch_bounds__(256) void fill_kernel(const int* __restrict__ ei, int E,
                                                   const int* __restrict__ row_start,
                                                   int* __restrict__ cursor,
                                                   int* __restrict__ srclist) {
    int e = blockIdx.x * 256 + threadIdx.x;
    if (e >= E) return;
    int src = ei[e];
    int dst = ei[E + e];
    int pos = row_start[dst] + atomicAdd(&cursor[dst], 1);
    srclist[pos] = src;
}

// ---------------------------------------------------------------------------
// Mean aggregation: one wave per node, float2 per lane (64*8B = 512B row)
// ---------------------------------------------------------------------------
__global__ __launch_bounds__(256) void aggregate_kernel(const float* __restrict__ feat,
                                                        const int* __restrict__ row_start,
                                                        const int* __restrict__ deg,
                                                        const int* __restrict__ srclist,
                                                        float* __restrict__ mean, int n) {
    int node = blockIdx.x * 4 + (threadIdx.x >> 6);
    if (node >= n) return;
    int lane = threadIdx.x & 63;
    int s0 = row_start[node];
    int d = deg[node];
    float ax = 0.f, ay = 0.f;
    for (int j = 0; j < d; ++j) {
        int src = srclist[s0 + j];
        const float2* row = (const float2*)(feat + (size_t)src * HID);
        float2 v = row[lane];
        ax += v.x;
        ay += v.y;
    }
    float inv = 1.0f / fmaxf((float)d, 1.0f);
    float2* o = (float2*)(mean + (size_t)node * HID);
    float2 r;
    r.x = ax * inv;
    r.y = ay * inv;
    o[lane] = r;
}

// ---------------------------------------------------------------------------
// Fused SAGE linear: out = mean @ Wl^T + root @ Wr^T + b   (folded K=256 GEMM)
// Block tile 64 rows x 128 cols, BK=16, 256 threads, 8x4 microtile/thread.
// ---------------------------------------------------------------------------
__global__ __launch_bounds__(256) void sage_gemm_kernel(const float* __restrict__ feat_mean,
                                                        const float* __restrict__ feat_root,
                                                        const float* __restrict__ Wl,
                                                        const float* __restrict__ Wr,
                                                        const float* __restrict__ bias,
                                                        float* __restrict__ out, int n) {
    __shared__ float As[16][64];
    __shared__ float Bs[16][128];

    int tid = threadIdx.x;
    int tx = tid & 31;   // column group: cols tx*4 .. +3
    int ty = tid >> 5;   // row group: rows ty*8 .. +7
    int row0 = blockIdx.x * 64;

    float acc[8][4];
#pragma unroll
    for (int r = 0; r < 8; ++r)
#pragma unroll
        for (int c = 0; c < 4; ++c) acc[r][c] = 0.f;

    int a_row = tid >> 2;        // 0..63
    int a_k4 = (tid & 3) * 4;    // 0,4,8,12
    int b_c = tid >> 2;          // 0..63
    int b_k4 = (tid & 3) * 4;

    for (int kk = 0; kk < 256; kk += 16) {
        const float* A = (kk < 128) ? feat_mean : feat_root;
        const float* W = (kk < 128) ? Wl : Wr;
        int ka = kk & 127;

        // stage A tile: As[k][row]
        {
            int gr = row0 + a_row;
            float4 v = make_float4(0.f, 0.f, 0.f, 0.f);
            if (gr < n) v = *(const float4*)(A + (size_t)gr * HID + ka + a_k4);
            As[a_k4 + 0][a_row] = v.x;
            As[a_k4 + 1][a_row] = v.y;
            As[a_k4 + 2][a_row] = v.z;
            As[a_k4 + 3][a_row] = v.w;
        }
        // stage B tile: Bs[k][c] = W[c][ka+k]
        {
            float4 v0 = *(const float4*)(W + (size_t)b_c * HID + ka + b_k4);
            float4 v1 = *(const float4*)(W + (size_t)(b_c + 64) * HID + ka + b_k4);
            Bs[b_k4 + 0][b_c] = v0.x;
            Bs[b_k4 + 1][b_c] = v0.y;
            Bs[b_k4 + 2][b_c] = v0.z;
            Bs[b_k4 + 3][b_c] = v0.w;
            Bs[b_k4 + 0][b_c + 64] = v1.x;
            Bs[b_k4 + 1][b_c + 64] = v1.y;
            Bs[b_k4 + 2][b_c + 64] = v1.z;
            Bs[b_k4 + 3][b_c + 64] = v1.w;
        }
        __syncthreads();

#pragma unroll
        for (int k = 0; k < 16; ++k) {
            float4 b = *(const float4*)&Bs[k][tx * 4];
            float4 a0 = *(const float4*)&As[k][ty * 8];
            float4 a1 = *(const float4*)&As[k][ty * 8 + 4];
            acc[0][0] += a0.x * b.x; acc[0][1] += a0.x * b.y; acc[0][2] += a0.x * b.z; acc[0][3] += a0.x * b.w;
            acc[1][0] += a0.y * b.x; acc[1][1] += a0.y * b.y; acc[1][2] += a0.y * b.z; acc[1][3] += a0.y * b.w;
            acc[2][0] += a0.z * b.x; acc[2][1] += a0.z * b.y; acc[2][2] += a0.z * b.z; acc[2][3] += a0.z * b.w;
            acc[3][0] += a0.w * b.x; acc[3][1] += a0.w * b.y; acc[3][2] += a0.w * b.z; acc[3][3] += a0.w * b.w;
            acc[4][0] += a1.x * b.x; acc[4][1] += a1.x * b.y; acc[4][2] += a1.x * b.z; acc[4][3] += a1.x * b.w;
            acc[5][0] += a1.y * b.x; acc[5][1] += a1.y * b.y; acc[5][2] += a1.y * b.z; acc[5][3] += a1.y * b.w;
            acc[6][0] += a1.z * b.x; acc[6][1] += a1.z * b.y; acc[6][2] += a1.z * b.z; acc[6][3] += a1.z * b.w;
            acc[7][0] += a1.w * b.x; acc[7][1] += a1.w * b.y; acc[7][2] += a1.w * b.z; acc[7][3] += a1.w * b.w;
        }
        __syncthreads();
    }

    float4 bv = *(const float4*)(bias + tx * 4);
#pragma unroll
    for (int r = 0; r < 8; ++r) {
        int gr = row0 + ty * 8 + r;
        if (gr < n) {
            float4 o;
            o.x = acc[r][0] + bv.x;
            o.y = acc[r][1] + bv.y;
            o.z = acc[r][2] + bv.z;
            o.w = acc[r][3] + bv.w;
            *(float4*)(out + (size_t)gr * HID + tx * 4) = o;
        }
    }
}

// ---------------------------------------------------------------------------
// Global add pool: batch is sorted; run-length accumulate, flush on change
// ---------------------------------------------------------------------------
__global__ __launch_bounds__(128) void pool_kernel(const float* __restrict__ h,
                                                   const int* __restrict__ batch,
                                                   float* __restrict__ pooled, int n) {
    const int CH = 128;  // nodes per block
    int n0 = blockIdx.x * CH;
    if (n0 >= n) return;
    int n1 = min(n0 + CH, n);
    int c = threadIdx.x;
    int g = batch[n0];
    float acc = 0.f;
    for (int i = n0; i < n1; ++i) {
        int gi = batch[i];
        if (gi != g) {
            atomicAdd(&pooled[g * HID + c], acc);
            acc = 0.f;
            g = gi;
        }
        acc += h[(size_t)i * HID + c];
    }
    atomicAdd(&pooled[g * HID + c], acc);
}

// ---------------------------------------------------------------------------
// Tail: lin1 + BN(eval) + relu + lin2. One block (128 thr) per graph.
// lin1_w staged transposed in LDS in two 64-k chunks with XOR swizzle.
// ---------------------------------------------------------------------------
__global__ __launch_bounds__(128) void tail_kernel(const float* __restrict__ pooled,
                                                   const float* __restrict__ lin1_w,
                                                   const float* __restrict__ lin1_b,
                                                   const float* __restrict__ lin2_w,
                                                   const float* __restrict__ lin2_b,
                                                   const float* __restrict__ gamma,
                                                   const float* __restrict__ beta,
                                                   const float* __restrict__ rmean,
                                                   const float* __restrict__ rvar,
                                                   float* __restrict__ out) {
    __shared__ float Wt[64 * 128];  // Wt[k][c ^ (k&31)] = lin1_w[c][k0+k]
    __shared__ float p[128];
    __shared__ float tbuf[128];
    int g = blockIdx.x;
    int c = threadIdx.x;
    p[c] = pooled[g * HID + c];
    float acc = lin1_b[c];
    int kk = c & 63;
    int chalf = c >> 6;
    for (int k0 = 0; k0 < 128; k0 += 64) {
        __syncthreads();
        for (int i = 0; i < 64; ++i) {
            int crow = i * 2 + chalf;
            float v = lin1_w[crow * HID + k0 + kk];
            Wt[kk * 128 + (crow ^ (kk & 31))] = v;
        }
        __syncthreads();
#pragma unroll
        for (int k = 0; k < 64; ++k) {
            acc += p[k0 + k] * Wt[k * 128 + (c ^ (k & 31))];
        }
    }
    float v = (acc - rmean[c]) * rsqrtf(rvar[c] + BN_EPS) * gamma[c] + beta[c];
    v = fmaxf(v, 0.f);
    tbuf[c] = v;
    __syncthreads();
    int j = c >> 6;
    int lane = c & 63;
    float partial = tbuf[lane] * lin2_w[j * HID + lane] +
                    tbuf[lane + 64] * lin2_w[j * HID + lane + 64];
    for (int off = 32; off > 0; off >>= 1) partial += __shfl_down(partial, off);
    if (lane == 0) out[g * 2 + j] = partial + lin2_b[j];
}

// ---------------------------------------------------------------------------
extern "C" void kernel_launch(void* const* d_in, const int* in_sizes, int n_in,
                              void* d_out, int out_size, void* d_ws, size_t ws_size,
                              hipStream_t stream) {
    const float* x = (const float*)d_in[0];
    const int* ei = (const int*)d_in[1];      // [2][E]
    const int* batch = (const int*)d_in[2];   // [N]
    const float* W1l = (const float*)d_in[3];
    const float* b1 = (const float*)d_in[4];
    const float* W1r = (const float*)d_in[5];
    const float* W2l = (const float*)d_in[6];
    const float* b2 = (const float*)d_in[7];
    const float* W2r = (const float*)d_in[8];
    const float* lin1_w = (const float*)d_in[9];
    const float* lin1_b = (const float*)d_in[10];
    const float* lin2_w = (const float*)d_in[11];
    const float* lin2_b = (const float*)d_in[12];
    const float* gamma = (const float*)d_in[13];
    const float* beta = (const float*)d_in[14];
    const float* rmean = (const float*)d_in[15];
    const float* rvar = (const float*)d_in[16];
    float* out = (float*)d_out;

    const int N = NN, E = NE;

    // workspace carve (256B aligned)
    char* p = (char*)d_ws;
    auto carve = [&](size_t bytes) {
        void* r = (void*)p;
        p += (bytes + 255) & ~(size_t)255;
        return r;
    };
    int* deg = (int*)carve((size_t)N * 4);
    int* row_start = (int*)carve((size_t)N * 4);
    int* cursor = (int*)carve((size_t)N * 4);
    int* bsums = (int*)carve(1024 * 4);
    int* srclist = (int*)carve((size_t)E * 4);
    float* meanb = (float*)carve((size_t)N * HID * 4);
    float* h1 = (float*)carve((size_t)N * HID * 4);
    float* h2 = (float*)carve((size_t)N * HID * 4);
    float* pooled = (float*)carve((size_t)NG * HID * 4);

    hipMemsetAsync(deg, 0, (size_t)N * 4, stream);
    hipMemsetAsync(cursor, 0, (size_t)N * 4, stream);
    hipMemsetAsync(pooled, 0, (size_t)NG * HID * 4, stream);

    const int scanBlocks = (N + 255) / 256;  // 196
    hist_kernel<<<(E + 255) / 256, 256, 0, stream>>>(ei, E, deg);
    scan1_kernel<<<scanBlocks, 256, 0, stream>>>(deg, row_start, bsums, N);
    scan2_kernel<<<1, 256, 0, stream>>>(bsums, scanBlocks);
    scan3_kernel<<<scanBlocks, 256, 0, stream>>>(row_start, bsums, N);
    fill_kernel<<<(E + 255) / 256, 256, 0, stream>>>(ei, E, row_start, cursor, srclist);

    // layer 1
    aggregate_kernel<<<(N + 3) / 4, 256, 0, stream>>>(x, row_start, deg, srclist, meanb, N);
    sage_gemm_kernel<<<(N + 63) / 64, 256, 0, stream>>>(meanb, x, W1l, W1r, b1, h1, N);
    // layer 2
    aggregate_kernel<<<(N + 3) / 4, 256, 0, stream>>>(h1, row_start, deg, srclist, meanb, N);
    sage_gemm_kernel<<<(N + 63) / 64, 256, 0, stream>>>(meanb, h1, W2l, W2r, b2, h2, N);
    // pool + tail
    pool_kernel<<<(N + 127) / 128, 128, 0, stream>>>(h2, batch, pooled, N);
    tail_kernel<<<NG, 128, 0, stream>>>(pooled, lin1_w, lin1_b, lin2_w, lin2_b,
                                        gamma, beta, rmean, rvar, out);
}

// Round 2
// 451.381 us; speedup vs baseline: 1.1349x; 1.1349x over previous
//
#include <hip/hip_runtime.h>
#include <hip/hip_bf16.h>

// Problem constants (match reference)
#define NN 50000
#define NE 800000
#define HID 128
#define NG 512
#define BN_EPS 1e-5f

// ---------------------------------------------------------------------------
// CSR build: histogram -> exclusive scan -> fill
// ---------------------------------------------------------------------------
__global__ __launch_bounds__(256) void hist_kernel(const int* __restrict__ ei,
                                                   int E, int* __restrict__ deg) {
    int e = blockIdx.x * 256 + threadIdx.x;
    if (e >= E) return;
    int dst = ei[E + e];
    atomicAdd(&deg[dst], 1);
}

__global__ __launch_bounds__(256) void scan1_kernel(const int* __restrict__ deg,
                                                    int* __restrict__ row_start,
                                                    int* __restrict__ bsums, int n) {
    __shared__ int s[256];
    int i = blockIdx.x * 256 + threadIdx.x;
    int v = (i < n) ? deg[i] : 0;
    s[threadIdx.x] = v;
    __syncthreads();
    for (int off = 1; off < 256; off <<= 1) {
        int t = (threadIdx.x >= off) ? s[threadIdx.x - off] : 0;
        __syncthreads();
        s[threadIdx.x] += t;
        __syncthreads();
    }
    if (i < n) row_start[i] = s[threadIdx.x] - v;  // exclusive
    if (threadIdx.x == 255) bsums[blockIdx.x] = s[255];
}

__global__ __launch_bounds__(256) void scan2_kernel(int* __restrict__ bsums, int nb) {
    __shared__ int s[256];
    int v = (threadIdx.x < nb) ? bsums[threadIdx.x] : 0;
    s[threadIdx.x] = v;
    __syncthreads();
    for (int off = 1; off < 256; off <<= 1) {
        int t = (threadIdx.x >= off) ? s[threadIdx.x - off] : 0;
        __syncthreads();
        s[threadIdx.x] += t;
        __syncthreads();
    }
    if (threadIdx.x < nb) bsums[threadIdx.x] = s[threadIdx.x] - v;  // exclusive
}

__global__ __launch_bounds__(256) void scan3_kernel(int* __restrict__ row_start,
                                                    const int* __restrict__ bsums, int n) {
    int i = blockIdx.x * 256 + threadIdx.x;
    if (i < n) row_start[i] += bsums[blockIdx.x];
}

__global__ __launch_bounds__(256) void fill_kernel(const int* __restrict__ ei, int E,
                                                   const int* __restrict__ row_start,
                                                   int* __restrict__ cursor,
                                                   int* __restrict__ srclist) {
    int e = blockIdx.x * 256 + threadIdx.x;
    if (e >= E) return;
    int src = ei[e];
    int dst = ei[E + e];
    int pos = row_start[dst] + atomicAdd(&cursor[dst], 1);
    srclist[pos] = src;
}

// ---------------------------------------------------------------------------
// Mean aggregation: one wave per node, float2 per lane (64*8B = 512B row).
// Neighbor loop unrolled x4: 4 independent row loads in flight per wave
// (2KB/wave MLP) to cover L2/LLC latency.
// ---------------------------------------------------------------------------
__global__ __launch_bounds__(256) void aggregate_kernel(const float* __restrict__ feat,
                                                        const int* __restrict__ row_start,
                                                        const int* __restrict__ deg,
                                                        const int* __restrict__ srclist,
                                                        float* __restrict__ mean, int n) {
    int node = blockIdx.x * 4 + (threadIdx.x >> 6);
    if (node >= n) return;
    int lane = threadIdx.x & 63;
    int s0 = row_start[node];
    int d = deg[node];
    float ax = 0.f, ay = 0.f;
    int j = 0;
    for (; j + 4 <= d; j += 4) {
        int i0 = srclist[s0 + j + 0];
        int i1 = srclist[s0 + j + 1];
        int i2 = srclist[s0 + j + 2];
        int i3 = srclist[s0 + j + 3];
        float2 v0 = ((const float2*)(feat + (size_t)i0 * HID))[lane];
        float2 v1 = ((const float2*)(feat + (size_t)i1 * HID))[lane];
        float2 v2 = ((const float2*)(feat + (size_t)i2 * HID))[lane];
        float2 v3 = ((const float2*)(feat + (size_t)i3 * HID))[lane];
        ax += v0.x + v1.x + v2.x + v3.x;
        ay += v0.y + v1.y + v2.y + v3.y;
    }
    for (; j < d; ++j) {
        int src = srclist[s0 + j];
        float2 v = ((const float2*)(feat + (size_t)src * HID))[lane];
        ax += v.x;
        ay += v.y;
    }
    float inv = 1.0f / fmaxf((float)d, 1.0f);
    float2* o = (float2*)(mean + (size_t)node * HID);
    float2 r;
    r.x = ax * inv;
    r.y = ay * inv;
    o[lane] = r;
}

// ---------------------------------------------------------------------------
// Fused SAGE linear: out = mean @ Wl^T + root @ Wr^T + b   (folded K=256 GEMM)
// Block tile 128x128, BK=16, 256 threads, 8x8 microtile/thread.
// LDS traffic: 16 floats per 64 FMAs/thread -> ~67% VALU ceiling (LDS-bound).
// ---------------------------------------------------------------------------
__global__ __launch_bounds__(256) void sage_gemm_kernel(const float* __restrict__ feat_mean,
                                                        const float* __restrict__ feat_root,
                                                        const float* __restrict__ Wl,
                                                        const float* __restrict__ Wr,
                                                        const float* __restrict__ bias,
                                                        float* __restrict__ out, int n) {
    __shared__ float As[16][128];
    __shared__ float Bs[16][128];

    int tid = threadIdx.x;
    int tx = tid & 15;   // col group: cols tx*8 .. +7
    int ty = tid >> 4;   // row group: rows ty*8 .. +7
    int row0 = blockIdx.x * 128;

    float acc[8][8];
#pragma unroll
    for (int r = 0; r < 8; ++r)
#pragma unroll
        for (int c = 0; c < 8; ++c) acc[r][c] = 0.f;

    int ld_row = tid >> 1;        // 0..127
    int ld_k8 = (tid & 1) * 8;    // 0 or 8

    for (int kk = 0; kk < 256; kk += 16) {
        const float* A = (kk < 128) ? feat_mean : feat_root;
        const float* W = (kk < 128) ? Wl : Wr;
        int ka = kk & 127;

        // global loads into regs (before barrier so they overlap prior compute)
        int gr = row0 + ld_row;
        float4 a0 = make_float4(0.f, 0.f, 0.f, 0.f), a1 = a0;
        if (gr < n) {
            a0 = *(const float4*)(A + (size_t)gr * HID + ka + ld_k8);
            a1 = *(const float4*)(A + (size_t)gr * HID + ka + ld_k8 + 4);
        }
        float4 b0 = *(const float4*)(W + (size_t)ld_row * HID + ka + ld_k8);
        float4 b1 = *(const float4*)(W + (size_t)ld_row * HID + ka + ld_k8 + 4);

        __syncthreads();  // previous tile fully consumed
        As[ld_k8 + 0][ld_row] = a0.x;
        As[ld_k8 + 1][ld_row] = a0.y;
        As[ld_k8 + 2][ld_row] = a0.z;
        As[ld_k8 + 3][ld_row] = a0.w;
        As[ld_k8 + 4][ld_row] = a1.x;
        As[ld_k8 + 5][ld_row] = a1.y;
        As[ld_k8 + 6][ld_row] = a1.z;
        As[ld_k8 + 7][ld_row] = a1.w;
        Bs[ld_k8 + 0][ld_row] = b0.x;
        Bs[ld_k8 + 1][ld_row] = b0.y;
        Bs[ld_k8 + 2][ld_row] = b0.z;
        Bs[ld_k8 + 3][ld_row] = b0.w;
        Bs[ld_k8 + 4][ld_row] = b1.x;
        Bs[ld_k8 + 5][ld_row] = b1.y;
        Bs[ld_k8 + 6][ld_row] = b1.z;
        Bs[ld_k8 + 7][ld_row] = b1.w;
        __syncthreads();

#pragma unroll
        for (int k = 0; k < 16; ++k) {
            float4 bv0 = *(const float4*)&Bs[k][tx * 8];
            float4 bv1 = *(const float4*)&Bs[k][tx * 8 + 4];
            float4 av0 = *(const float4*)&As[k][ty * 8];
            float4 av1 = *(const float4*)&As[k][ty * 8 + 4];
            float a_[8] = {av0.x, av0.y, av0.z, av0.w, av1.x, av1.y, av1.z, av1.w};
            float b_[8] = {bv0.x, bv0.y, bv0.z, bv0.w, bv1.x, bv1.y, bv1.z, bv1.w};
#pragma unroll
            for (int r = 0; r < 8; ++r)
#pragma unroll
                for (int c = 0; c < 8; ++c) acc[r][c] += a_[r] * b_[c];
        }
        __syncthreads();
    }

    float4 bi0 = *(const float4*)(bias + tx * 8);
    float4 bi1 = *(const float4*)(bias + tx * 8 + 4);
#pragma unroll
    for (int r = 0; r < 8; ++r) {
        int gr = row0 + ty * 8 + r;
        if (gr < n) {
            float4 o0, o1;
            o0.x = acc[r][0] + bi0.x;
            o0.y = acc[r][1] + bi0.y;
            o0.z = acc[r][2] + bi0.z;
            o0.w = acc[r][3] + bi0.w;
            o1.x = acc[r][4] + bi1.x;
            o1.y = acc[r][5] + bi1.y;
            o1.z = acc[r][6] + bi1.z;
            o1.w = acc[r][7] + bi1.w;
            *(float4*)(out + (size_t)gr * HID + tx * 8) = o0;
            *(float4*)(out + (size_t)gr * HID + tx * 8 + 4) = o1;
        }
    }
}

// ---------------------------------------------------------------------------
// Global add pool: batch is sorted; run-length accumulate, flush on change
// ---------------------------------------------------------------------------
__global__ __launch_bounds__(128) void pool_kernel(const float* __restrict__ h,
                                                   const int* __restrict__ batch,
                                                   float* __restrict__ pooled, int n) {
    const int CH = 128;  // nodes per block
    int n0 = blockIdx.x * CH;
    if (n0 >= n) return;
    int n1 = min(n0 + CH, n);
    int c = threadIdx.x;
    int g = batch[n0];
    float acc = 0.f;
    for (int i = n0; i < n1; ++i) {
        int gi = batch[i];
        if (gi != g) {
            atomicAdd(&pooled[g * HID + c], acc);
            acc = 0.f;
            g = gi;
        }
        acc += h[(size_t)i * HID + c];
    }
    atomicAdd(&pooled[g * HID + c], acc);
}

// ---------------------------------------------------------------------------
// Tail: lin1 + BN(eval) + relu + lin2. One block (128 thr) per graph.
// ---------------------------------------------------------------------------
__global__ __launch_bounds__(128) void tail_kernel(const float* __restrict__ pooled,
                                                   const float* __restrict__ lin1_w,
                                                   const float* __restrict__ lin1_b,
                                                   const float* __restrict__ lin2_w,
                                                   const float* __restrict__ lin2_b,
                                                   const float* __restrict__ gamma,
                                                   const float* __restrict__ beta,
                                                   const float* __restrict__ rmean,
                                                   const float* __restrict__ rvar,
                                                   float* __restrict__ out) {
    __shared__ float Wt[64 * 128];  // Wt[k][c ^ (k&31)] = lin1_w[c][k0+k]
    __shared__ float p[128];
    __shared__ float tbuf[128];
    int g = blockIdx.x;
    int c = threadIdx.x;
    p[c] = pooled[g * HID + c];
    float acc = lin1_b[c];
    int kk = c & 63;
    int chalf = c >> 6;
    for (int k0 = 0; k0 < 128; k0 += 64) {
        __syncthreads();
        for (int i = 0; i < 64; ++i) {
            int crow = i * 2 + chalf;
            float v = lin1_w[crow * HID + k0 + kk];
            Wt[kk * 128 + (crow ^ (kk & 31))] = v;
        }
        __syncthreads();
#pragma unroll
        for (int k = 0; k < 64; ++k) {
            acc += p[k0 + k] * Wt[k * 128 + (c ^ (k & 31))];
        }
    }
    float v = (acc - rmean[c]) * rsqrtf(rvar[c] + BN_EPS) * gamma[c] + beta[c];
    v = fmaxf(v, 0.f);
    tbuf[c] = v;
    __syncthreads();
    int j = c >> 6;
    int lane = c & 63;
    float partial = tbuf[lane] * lin2_w[j * HID + lane] +
                    tbuf[lane + 64] * lin2_w[j * HID + lane + 64];
    for (int off = 32; off > 0; off >>= 1) partial += __shfl_down(partial, off);
    if (lane == 0) out[g * 2 + j] = partial + lin2_b[j];
}

// ---------------------------------------------------------------------------
extern "C" void kernel_launch(void* const* d_in, const int* in_sizes, int n_in,
                              void* d_out, int out_size, void* d_ws, size_t ws_size,
                              hipStream_t stream) {
    const float* x = (const float*)d_in[0];
    const int* ei = (const int*)d_in[1];      // [2][E]
    const int* batch = (const int*)d_in[2];   // [N]
    const float* W1l = (const float*)d_in[3];
    const float* b1 = (const float*)d_in[4];
    const float* W1r = (const float*)d_in[5];
    const float* W2l = (const float*)d_in[6];
    const float* b2 = (const float*)d_in[7];
    const float* W2r = (const float*)d_in[8];
    const float* lin1_w = (const float*)d_in[9];
    const float* lin1_b = (const float*)d_in[10];
    const float* lin2_w = (const float*)d_in[11];
    const float* lin2_b = (const float*)d_in[12];
    const float* gamma = (const float*)d_in[13];
    const float* beta = (const float*)d_in[14];
    const float* rmean = (const float*)d_in[15];
    const float* rvar = (const float*)d_in[16];
    float* out = (float*)d_out;

    const int N = NN, E = NE;

    // workspace carve (256B aligned)
    char* p = (char*)d_ws;
    auto carve = [&](size_t bytes) {
        void* r = (void*)p;
        p += (bytes + 255) & ~(size_t)255;
        return r;
    };
    int* deg = (int*)carve((size_t)N * 4);
    int* row_start = (int*)carve((size_t)N * 4);
    int* cursor = (int*)carve((size_t)N * 4);
    int* bsums = (int*)carve(1024 * 4);
    int* srclist = (int*)carve((size_t)E * 4);
    float* meanb = (float*)carve((size_t)N * HID * 4);
    float* h1 = (float*)carve((size_t)N * HID * 4);
    float* h2 = (float*)carve((size_t)N * HID * 4);
    float* pooled = (float*)carve((size_t)NG * HID * 4);

    hipMemsetAsync(deg, 0, (size_t)N * 4, stream);
    hipMemsetAsync(cursor, 0, (size_t)N * 4, stream);
    hipMemsetAsync(pooled, 0, (size_t)NG * HID * 4, stream);

    const int scanBlocks = (N + 255) / 256;  // 196
    hist_kernel<<<(E + 255) / 256, 256, 0, stream>>>(ei, E, deg);
    scan1_kernel<<<scanBlocks, 256, 0, stream>>>(deg, row_start, bsums, N);
    scan2_kernel<<<1, 256, 0, stream>>>(bsums, scanBlocks);
    scan3_kernel<<<scanBlocks, 256, 0, stream>>>(row_start, bsums, N);
    fill_kernel<<<(E + 255) / 256, 256, 0, stream>>>(ei, E, row_start, cursor, srclist);

    // layer 1
    aggregate_kernel<<<(N + 3) / 4, 256, 0, stream>>>(x, row_start, deg, srclist, meanb, N);
    sage_gemm_kernel<<<(N + 127) / 128, 256, 0, stream>>>(meanb, x, W1l, W1r, b1, h1, N);
    // layer 2
    aggregate_kernel<<<(N + 3) / 4, 256, 0, stream>>>(h1, row_start, deg, srclist, meanb, N);
    sage_gemm_kernel<<<(N + 127) / 128, 256, 0, stream>>>(meanb, h1, W2l, W2r, b2, h2, N);
    // pool + tail
    pool_kernel<<<(N + 127) / 128, 128, 0, stream>>>(h2, batch, pooled, N);
    tail_kernel<<<NG, 128, 0, stream>>>(pooled, lin1_w, lin1_b, lin2_w, lin2_b,
                                        gamma, beta, rmean, rvar, out);
}

// Round 3
// 336.921 us; speedup vs baseline: 1.5204x; 1.3397x over previous
//
#include <hip/hip_runtime.h>
#include <hip/hip_bf16.h>

// Problem constants (match reference)
#define NN 50000
#define NE 800000
#define HID 128
#define NG 512
#define BN_EPS 1e-5f

typedef __attribute__((ext_vector_type(8))) short bf16x8;
typedef __attribute__((ext_vector_type(4))) float f32x4;

__device__ __forceinline__ ushort f2bf(float f) {
    uint u = __float_as_uint(f);
    uint r = (u + 0x7fffu + ((u >> 16) & 1u)) >> 16;
    return (ushort)r;
}
__device__ __forceinline__ float bf_lo(uint v) { return __uint_as_float(v << 16); }
__device__ __forceinline__ float bf_hi(uint v) { return __uint_as_float(v & 0xffff0000u); }

// ---------------------------------------------------------------------------
// CSR build: histogram -> exclusive scan -> fill
// ---------------------------------------------------------------------------
__global__ __launch_bounds__(256) void hist_kernel(const int* __restrict__ ei,
                                                   int E, int* __restrict__ deg) {
    int e = blockIdx.x * 256 + threadIdx.x;
    if (e >= E) return;
    int dst = ei[E + e];
    atomicAdd(&deg[dst], 1);
}

__global__ __launch_bounds__(256) void scan1_kernel(const int* __restrict__ deg,
                                                    int* __restrict__ row_start,
                                                    int* __restrict__ bsums, int n) {
    __shared__ int s[256];
    int i = blockIdx.x * 256 + threadIdx.x;
    int v = (i < n) ? deg[i] : 0;
    s[threadIdx.x] = v;
    __syncthreads();
    for (int off = 1; off < 256; off <<= 1) {
        int t = (threadIdx.x >= off) ? s[threadIdx.x - off] : 0;
        __syncthreads();
        s[threadIdx.x] += t;
        __syncthreads();
    }
    if (i < n) row_start[i] = s[threadIdx.x] - v;  // exclusive
    if (threadIdx.x == 255) bsums[blockIdx.x] = s[255];
}

__global__ __launch_bounds__(256) void scan2_kernel(int* __restrict__ bsums, int nb) {
    __shared__ int s[256];
    int v = (threadIdx.x < nb) ? bsums[threadIdx.x] : 0;
    s[threadIdx.x] = v;
    __syncthreads();
    for (int off = 1; off < 256; off <<= 1) {
        int t = (threadIdx.x >= off) ? s[threadIdx.x - off] : 0;
        __syncthreads();
        s[threadIdx.x] += t;
        __syncthreads();
    }
    if (threadIdx.x < nb) bsums[threadIdx.x] = s[threadIdx.x] - v;  // exclusive
}

__global__ __launch_bounds__(256) void scan3_kernel(int* __restrict__ row_start,
                                                    const int* __restrict__ bsums, int n) {
    int i = blockIdx.x * 256 + threadIdx.x;
    if (i < n) row_start[i] += bsums[blockIdx.x];
}

__global__ __launch_bounds__(256) void fill_kernel(const int* __restrict__ ei, int E,
                                                   const int* __restrict__ row_start,
                                                   int* __restrict__ cursor,
                                                   int* __restrict__ srclist) {
    int e = blockIdx.x * 256 + threadIdx.x;
    if (e >= E) return;
    int src = ei[e];
    int dst = ei[E + e];
    int pos = row_start[dst] + atomicAdd(&cursor[dst], 1);
    srclist[pos] = src;
}

// ---------------------------------------------------------------------------
// fp32 -> bf16 bulk convert (x features), 4 elems/thread
// ---------------------------------------------------------------------------
__global__ __launch_bounds__(256) void convert_bf16_kernel(const float* __restrict__ in,
                                                           ushort* __restrict__ out, int n4) {
    int i = blockIdx.x * 256 + threadIdx.x;
    if (i >= n4) return;
    float4 v = ((const float4*)in)[i];
    ushort4 o;
    o.x = f2bf(v.x);
    o.y = f2bf(v.y);
    o.z = f2bf(v.z);
    o.w = f2bf(v.w);
    ((ushort4*)out)[i] = o;
}

// ---------------------------------------------------------------------------
// Pack weights into MFMA B-fragment order (bf16).
// Wp[m][g][lane][j], g = tile*4+chunk (tile: 16 output cols, chunk: 32 k).
// lane holds W[tile*16 + (lane&15)][chunk*32 + (lane>>4)*8 + j], j=0..7.
// grid = 4*32 blocks of 64 threads (1 wave each); block b: matrix b>>5, g=b&31.
// ---------------------------------------------------------------------------
__global__ __launch_bounds__(64) void wprep_kernel(const float* __restrict__ W0,
                                                   const float* __restrict__ W1,
                                                   const float* __restrict__ W2,
                                                   const float* __restrict__ W3,
                                                   ushort* __restrict__ Wp) {
    int b = blockIdx.x;
    int m = b >> 5;
    int g = b & 31;
    int tile = g >> 2;
    int chunk = g & 3;
    int lane = threadIdx.x;
    const float* W = (m == 0) ? W0 : (m == 1) ? W1 : (m == 2) ? W2 : W3;
    int col = tile * 16 + (lane & 15);
    int k0 = chunk * 32 + (lane >> 4) * 8;
    ushort* dst = Wp + ((size_t)b * 64 + lane) * 8;
#pragma unroll
    for (int j = 0; j < 8; ++j) dst[j] = f2bf(W[col * HID + k0 + j]);
}

// ---------------------------------------------------------------------------
// Mean aggregation over bf16 features: one wave per node, uint (2 bf16)/lane,
// x4 unrolled neighbor loop for MLP. fp32 accumulate, bf16 output.
// ---------------------------------------------------------------------------
__global__ __launch_bounds__(256) void aggregate_kernel(const ushort* __restrict__ feat,
                                                        const int* __restrict__ row_start,
                                                        const int* __restrict__ deg,
                                                        const int* __restrict__ srclist,
                                                        ushort* __restrict__ mean, int n) {
    int node = blockIdx.x * 4 + (threadIdx.x >> 6);
    if (node >= n) return;
    int lane = threadIdx.x & 63;
    const uint* fb = (const uint*)feat;  // row stride 64 uints
    int s0 = row_start[node];
    int d = deg[node];
    float ax = 0.f, ay = 0.f;
    int j = 0;
    for (; j + 4 <= d; j += 4) {
        int i0 = srclist[s0 + j + 0];
        int i1 = srclist[s0 + j + 1];
        int i2 = srclist[s0 + j + 2];
        int i3 = srclist[s0 + j + 3];
        uint v0 = fb[(size_t)i0 * 64 + lane];
        uint v1 = fb[(size_t)i1 * 64 + lane];
        uint v2 = fb[(size_t)i2 * 64 + lane];
        uint v3 = fb[(size_t)i3 * 64 + lane];
        ax += bf_lo(v0) + bf_lo(v1) + bf_lo(v2) + bf_lo(v3);
        ay += bf_hi(v0) + bf_hi(v1) + bf_hi(v2) + bf_hi(v3);
    }
    for (; j < d; ++j) {
        int src = srclist[s0 + j];
        uint v = fb[(size_t)src * 64 + lane];
        ax += bf_lo(v);
        ay += bf_hi(v);
    }
    float inv = 1.0f / fmaxf((float)d, 1.0f);
    uint packed = (uint)f2bf(ax * inv) | ((uint)f2bf(ay * inv) << 16);
    ((uint*)mean)[(size_t)node * 64 + lane] = packed;
}

// ---------------------------------------------------------------------------
// MFMA SAGE linear: out = mean @ Wl^T + root @ Wr^T + b.
// One wave per 16 rows x 128 cols; no LDS, no barriers.
// A-fragments direct from global (L1-resident per block);
// B-fragments from packed Wp (L2-resident, coalesced 16B/lane).
// 50000 = 16*3125 exactly -> whole-wave guard only.
// ---------------------------------------------------------------------------
template <bool OUT_BF16>
__global__ __launch_bounds__(256) void sage_gemm_mfma(const ushort* __restrict__ Amean,
                                                      const ushort* __restrict__ Aroot,
                                                      const ushort* __restrict__ WpL,  // 2 matrices
                                                      const float* __restrict__ bias,
                                                      void* __restrict__ out, int nwaves) {
    int w = blockIdx.x * 4 + (threadIdx.x >> 6);
    if (w >= nwaves) return;
    int lane = threadIdx.x & 63;
    int mrow = lane & 15;
    int quad = lane >> 4;
    int r0 = w * 16;

    f32x4 acc[8];
#pragma unroll
    for (int t = 0; t < 8; ++t) acc[t] = (f32x4){0.f, 0.f, 0.f, 0.f};

    const ushort* arow_m = Amean + ((size_t)(r0 + mrow)) * HID + quad * 8;
    const ushort* arow_r = Aroot + ((size_t)(r0 + mrow)) * HID + quad * 8;

#pragma unroll
    for (int half = 0; half < 2; ++half) {
        const ushort* arow = half ? arow_r : arow_m;
        const ushort* wb = WpL + (size_t)half * 16384 + (size_t)lane * 8;
#pragma unroll
        for (int c = 0; c < 4; ++c) {
            bf16x8 a = *(const bf16x8*)(arow + c * 32);
#pragma unroll
            for (int t = 0; t < 8; ++t) {
                bf16x8 b = *(const bf16x8*)(wb + (size_t)(t * 4 + c) * 512);
                acc[t] = __builtin_amdgcn_mfma_f32_16x16x32_bf16(a, b, acc[t], 0, 0, 0);
            }
        }
    }

#pragma unroll
    for (int t = 0; t < 8; ++t) {
        int col = t * 16 + mrow;
        float bv = bias[col];
#pragma unroll
        for (int r = 0; r < 4; ++r) {
            int row = r0 + quad * 4 + r;
            float v = acc[t][r] + bv;
            if (OUT_BF16)
                ((ushort*)out)[(size_t)row * HID + col] = f2bf(v);
            else
                ((float*)out)[(size_t)row * HID + col] = v;
        }
    }
}

// ---------------------------------------------------------------------------
// Global add pool: batch is sorted; run-length accumulate, flush on change
// ---------------------------------------------------------------------------
__global__ __launch_bounds__(128) void pool_kernel(const float* __restrict__ h,
                                                   const int* __restrict__ batch,
                                                   float* __restrict__ pooled, int n) {
    const int CH = 128;  // nodes per block
    int n0 = blockIdx.x * CH;
    if (n0 >= n) return;
    int n1 = min(n0 + CH, n);
    int c = threadIdx.x;
    int g = batch[n0];
    float acc = 0.f;
    for (int i = n0; i < n1; ++i) {
        int gi = batch[i];
        if (gi != g) {
            atomicAdd(&pooled[g * HID + c], acc);
            acc = 0.f;
            g = gi;
        }
        acc += h[(size_t)i * HID + c];
    }
    atomicAdd(&pooled[g * HID + c], acc);
}

// ---------------------------------------------------------------------------
// Tail: lin1 + BN(eval) + relu + lin2. One block (128 thr) per graph.
// ---------------------------------------------------------------------------
__global__ __launch_bounds__(128) void tail_kernel(const float* __restrict__ pooled,
                                                   const float* __restrict__ lin1_w,
                                                   const float* __restrict__ lin1_b,
                                                   const float* __restrict__ lin2_w,
                                                   const float* __restrict__ lin2_b,
                                                   const float* __restrict__ gamma,
                                                   const float* __restrict__ beta,
                                                   const float* __restrict__ rmean,
                                                   const float* __restrict__ rvar,
                                                   float* __restrict__ out) {
    __shared__ float Wt[64 * 128];  // Wt[k][c ^ (k&31)] = lin1_w[c][k0+k]
    __shared__ float p[128];
    __shared__ float tbuf[128];
    int g = blockIdx.x;
    int c = threadIdx.x;
    p[c] = pooled[g * HID + c];
    float acc = lin1_b[c];
    int kk = c & 63;
    int chalf = c >> 6;
    for (int k0 = 0; k0 < 128; k0 += 64) {
        __syncthreads();
        for (int i = 0; i < 64; ++i) {
            int crow = i * 2 + chalf;
            float v = lin1_w[crow * HID + k0 + kk];
            Wt[kk * 128 + (crow ^ (kk & 31))] = v;
        }
        __syncthreads();
#pragma unroll
        for (int k = 0; k < 64; ++k) {
            acc += p[k0 + k] * Wt[k * 128 + (c ^ (k & 31))];
        }
    }
    float v = (acc - rmean[c]) * rsqrtf(rvar[c] + BN_EPS) * gamma[c] + beta[c];
    v = fmaxf(v, 0.f);
    tbuf[c] = v;
    __syncthreads();
    int j = c >> 6;
    int lane = c & 63;
    float partial = tbuf[lane] * lin2_w[j * HID + lane] +
                    tbuf[lane + 64] * lin2_w[j * HID + lane + 64];
    for (int off = 32; off > 0; off >>= 1) partial += __shfl_down(partial, off);
    if (lane == 0) out[g * 2 + j] = partial + lin2_b[j];
}

// ---------------------------------------------------------------------------
extern "C" void kernel_launch(void* const* d_in, const int* in_sizes, int n_in,
                              void* d_out, int out_size, void* d_ws, size_t ws_size,
                              hipStream_t stream) {
    const float* x = (const float*)d_in[0];
    const int* ei = (const int*)d_in[1];      // [2][E]
    const int* batch = (const int*)d_in[2];   // [N]
    const float* W1l = (const float*)d_in[3];
    const float* b1 = (const float*)d_in[4];
    const float* W1r = (const float*)d_in[5];
    const float* W2l = (const float*)d_in[6];
    const float* b2 = (const float*)d_in[7];
    const float* W2r = (const float*)d_in[8];
    const float* lin1_w = (const float*)d_in[9];
    const float* lin1_b = (const float*)d_in[10];
    const float* lin2_w = (const float*)d_in[11];
    const float* lin2_b = (const float*)d_in[12];
    const float* gamma = (const float*)d_in[13];
    const float* beta = (const float*)d_in[14];
    const float* rmean = (const float*)d_in[15];
    const float* rvar = (const float*)d_in[16];
    float* out = (float*)d_out;

    const int N = NN, E = NE;
    const int NWAVES = N / 16;  // 3125 exact

    // workspace carve (256B aligned)
    char* p = (char*)d_ws;
    auto carve = [&](size_t bytes) {
        void* r = (void*)p;
        p += (bytes + 255) & ~(size_t)255;
        return r;
    };
    int* deg_cursor = (int*)carve((size_t)2 * N * 4);  // deg | cursor, one memset
    int* deg = deg_cursor;
    int* cursor = deg_cursor + N;
    int* row_start = (int*)carve((size_t)N * 4);
    int* bsums = (int*)carve(1024 * 4);
    int* srclist = (int*)carve((size_t)E * 4);
    ushort* xb = (ushort*)carve((size_t)N * HID * 2);
    ushort* meanb = (ushort*)carve((size_t)N * HID * 2);
    ushort* h1 = (ushort*)carve((size_t)N * HID * 2);
    float* h2 = (float*)carve((size_t)N * HID * 4);
    float* pooled = (float*)carve((size_t)NG * HID * 4);
    ushort* Wp = (ushort*)carve(4 * 32 * 64 * 8 * 2);  // 128 KB

    hipMemsetAsync(deg_cursor, 0, (size_t)2 * N * 4, stream);
    hipMemsetAsync(pooled, 0, (size_t)NG * HID * 4, stream);

    const int scanBlocks = (N + 255) / 256;  // 196
    hist_kernel<<<(E + 255) / 256, 256, 0, stream>>>(ei, E, deg);
    scan1_kernel<<<scanBlocks, 256, 0, stream>>>(deg, row_start, bsums, N);
    scan2_kernel<<<1, 256, 0, stream>>>(bsums, scanBlocks);
    scan3_kernel<<<scanBlocks, 256, 0, stream>>>(row_start, bsums, N);
    fill_kernel<<<(E + 255) / 256, 256, 0, stream>>>(ei, E, row_start, cursor, srclist);

    // feature convert + weight pack
    convert_bf16_kernel<<<(N * HID / 4 + 255) / 256, 256, 0, stream>>>(x, xb, N * HID / 4);
    wprep_kernel<<<128, 64, 0, stream>>>(W1l, W1r, W2l, W2r, Wp);

    // layer 1 (bf16 out)
    aggregate_kernel<<<(N + 3) / 4, 256, 0, stream>>>(xb, row_start, deg, srclist, meanb, N);
    sage_gemm_mfma<true><<<(NWAVES + 3) / 4, 256, 0, stream>>>(meanb, xb, Wp, b1, h1, NWAVES);
    // layer 2 (fp32 out for pool)
    aggregate_kernel<<<(N + 3) / 4, 256, 0, stream>>>(h1, row_start, deg, srclist, meanb, N);
    sage_gemm_mfma<false><<<(NWAVES + 3) / 4, 256, 0, stream>>>(meanb, h1, Wp + 32768, b2, h2,
                                                                NWAVES);
    // pool + tail
    pool_kernel<<<(N + 127) / 128, 128, 0, stream>>>(h2, batch, pooled, N);
    tail_kernel<<<NG, 128, 0, stream>>>(pooled, lin1_w, lin1_b, lin2_w, lin2_b,
                                        gamma, beta, rmean, rvar, out);
}

// Round 4
// 271.303 us; speedup vs baseline: 1.8881x; 1.2419x over previous
//
#include <hip/hip_runtime.h>
#include <hip/hip_bf16.h>

// Problem constants (match reference)
#define NN 50000
#define NE 800000
#define HID 128
#define NG 512
#define BN_EPS 1e-5f

typedef __attribute__((ext_vector_type(8))) short bf16x8;
typedef __attribute__((ext_vector_type(4))) float f32x4;

__device__ __forceinline__ ushort f2bf(float f) {
    uint u = __float_as_uint(f);
    uint r = (u + 0x7fffu + ((u >> 16) & 1u)) >> 16;
    return (ushort)r;
}
__device__ __forceinline__ float bf_lo(uint v) { return __uint_as_float(v << 16); }
__device__ __forceinline__ float bf_hi(uint v) { return __uint_as_float(v & 0xffff0000u); }

// ---------------------------------------------------------------------------
// CSR build: histogram (captures per-edge rank) -> exclusive scan -> fill
// ---------------------------------------------------------------------------
__global__ __launch_bounds__(256) void hist_kernel(const int* __restrict__ ei,
                                                   int E, int* __restrict__ deg,
                                                   int* __restrict__ rank) {
    int e = blockIdx.x * 256 + threadIdx.x;
    if (e >= E) return;
    int dst = ei[E + e];
    rank[e] = atomicAdd(&deg[dst], 1);
}

__global__ __launch_bounds__(256) void scan1_kernel(const int* __restrict__ deg,
                                                    int* __restrict__ row_start,
                                                    int* __restrict__ bsums, int n) {
    __shared__ int s[256];
    int i = blockIdx.x * 256 + threadIdx.x;
    int v = (i < n) ? deg[i] : 0;
    s[threadIdx.x] = v;
    __syncthreads();
    for (int off = 1; off < 256; off <<= 1) {
        int t = (threadIdx.x >= off) ? s[threadIdx.x - off] : 0;
        __syncthreads();
        s[threadIdx.x] += t;
        __syncthreads();
    }
    if (i < n) row_start[i] = s[threadIdx.x] - v;  // exclusive
    if (threadIdx.x == 255) bsums[blockIdx.x] = s[255];
}

__global__ __launch_bounds__(256) void scan2_kernel(int* __restrict__ bsums, int nb) {
    __shared__ int s[256];
    int v = (threadIdx.x < nb) ? bsums[threadIdx.x] : 0;
    s[threadIdx.x] = v;
    __syncthreads();
    for (int off = 1; off < 256; off <<= 1) {
        int t = (threadIdx.x >= off) ? s[threadIdx.x - off] : 0;
        __syncthreads();
        s[threadIdx.x] += t;
        __syncthreads();
    }
    if (threadIdx.x < nb) bsums[threadIdx.x] = s[threadIdx.x] - v;  // exclusive
}

__global__ __launch_bounds__(256) void scan3_kernel(int* __restrict__ row_start,
                                                    const int* __restrict__ bsums, int n) {
    int i = blockIdx.x * 256 + threadIdx.x;
    if (i < n) row_start[i] += bsums[blockIdx.x];
}

// atomic-free fill: pos comes from precomputed rank
__global__ __launch_bounds__(256) void fill_kernel(const int* __restrict__ ei, int E,
                                                   const int* __restrict__ row_start,
                                                   const int* __restrict__ rank,
                                                   int* __restrict__ srclist) {
    int e = blockIdx.x * 256 + threadIdx.x;
    if (e >= E) return;
    int src = ei[e];
    int dst = ei[E + e];
    srclist[row_start[dst] + rank[e]] = src;
}

// ---------------------------------------------------------------------------
// fp32 -> bf16 bulk convert (x features), 4 elems/thread
// ---------------------------------------------------------------------------
__global__ __launch_bounds__(256) void convert_bf16_kernel(const float* __restrict__ in,
                                                           ushort* __restrict__ out, int n4) {
    int i = blockIdx.x * 256 + threadIdx.x;
    if (i >= n4) return;
    float4 v = ((const float4*)in)[i];
    ushort4 o;
    o.x = f2bf(v.x);
    o.y = f2bf(v.y);
    o.z = f2bf(v.z);
    o.w = f2bf(v.w);
    ((ushort4*)out)[i] = o;
}

// ---------------------------------------------------------------------------
// Pack weights into MFMA B-fragment order (bf16).
// Wp[m][g][lane][j], g = tile*4+chunk (tile: 16 output cols, chunk: 32 k).
// lane holds W[tile*16 + (lane&15)][chunk*32 + (lane>>4)*8 + j], j=0..7.
// ---------------------------------------------------------------------------
__global__ __launch_bounds__(64) void wprep_kernel(const float* __restrict__ W0,
                                                   const float* __restrict__ W1,
                                                   const float* __restrict__ W2,
                                                   const float* __restrict__ W3,
                                                   ushort* __restrict__ Wp) {
    int b = blockIdx.x;
    int m = b >> 5;
    int g = b & 31;
    int tile = g >> 2;
    int chunk = g & 3;
    int lane = threadIdx.x;
    const float* W = (m == 0) ? W0 : (m == 1) ? W1 : (m == 2) ? W2 : W3;
    int col = tile * 16 + (lane & 15);
    int k0 = chunk * 32 + (lane >> 4) * 8;
    ushort* dst = Wp + ((size_t)b * 64 + lane) * 8;
#pragma unroll
    for (int j = 0; j < 8; ++j) dst[j] = f2bf(W[col * HID + k0 + j]);
}

// ---------------------------------------------------------------------------
// Mean aggregation (bf16): one wave per node.
// Lane layout: cl = lane&15 -> 16B column chunk (16 x uint4 = 256B row),
//              sub = lane>>4 -> 4 parallel neighbor slots.
// Main loop: 8 neighbors/iter (2 x 2KB in flight). Uniform trip count per wave.
// Cross-sub reduction via shfl_xor(16/32). fp32 accumulate, bf16 out.
// ---------------------------------------------------------------------------
__global__ __launch_bounds__(256) void aggregate_kernel(const ushort* __restrict__ feat,
                                                        const int* __restrict__ row_start,
                                                        const int* __restrict__ deg,
                                                        const int* __restrict__ srclist,
                                                        ushort* __restrict__ mean, int n) {
    int node = blockIdx.x * 4 + (threadIdx.x >> 6);
    if (node >= n) return;
    int lane = threadIdx.x & 63;
    int cl = lane & 15;
    int sub = lane >> 4;
    const uint4* fb = (const uint4*)feat;  // row stride = 16 uint4
    int s0 = row_start[node];
    int d = deg[node];

    float a[8];
#pragma unroll
    for (int i = 0; i < 8; ++i) a[i] = 0.f;

    int j = 0;
    for (; j + 8 <= d; j += 8) {
        int i0 = srclist[s0 + j + sub];
        int i1 = srclist[s0 + j + 4 + sub];
        uint4 v0 = fb[(size_t)i0 * 16 + cl];
        uint4 v1 = fb[(size_t)i1 * 16 + cl];
        a[0] += bf_lo(v0.x) + bf_lo(v1.x);
        a[1] += bf_hi(v0.x) + bf_hi(v1.x);
        a[2] += bf_lo(v0.y) + bf_lo(v1.y);
        a[3] += bf_hi(v0.y) + bf_hi(v1.y);
        a[4] += bf_lo(v0.z) + bf_lo(v1.z);
        a[5] += bf_hi(v0.z) + bf_hi(v1.z);
        a[6] += bf_lo(v0.w) + bf_lo(v1.w);
        a[7] += bf_hi(v0.w) + bf_hi(v1.w);
    }
    for (; j < d; j += 4) {
        int idx = j + sub;
        bool valid = idx < d;
        int safe = valid ? idx : (d - 1);
        int src = srclist[s0 + safe];
        uint4 v = fb[(size_t)src * 16 + cl];
        float s = valid ? 1.f : 0.f;
        a[0] += s * bf_lo(v.x);
        a[1] += s * bf_hi(v.x);
        a[2] += s * bf_lo(v.y);
        a[3] += s * bf_hi(v.y);
        a[4] += s * bf_lo(v.z);
        a[5] += s * bf_hi(v.z);
        a[6] += s * bf_lo(v.w);
        a[7] += s * bf_hi(v.w);
    }

#pragma unroll
    for (int i = 0; i < 8; ++i) {
        float v = a[i];
        v += __shfl_xor(v, 16);
        v += __shfl_xor(v, 32);
        a[i] = v;
    }

    if (sub == 0) {
        float inv = 1.0f / fmaxf((float)d, 1.0f);
        uint4 o;
        o.x = (uint)f2bf(a[0] * inv) | ((uint)f2bf(a[1] * inv) << 16);
        o.y = (uint)f2bf(a[2] * inv) | ((uint)f2bf(a[3] * inv) << 16);
        o.z = (uint)f2bf(a[4] * inv) | ((uint)f2bf(a[5] * inv) << 16);
        o.w = (uint)f2bf(a[6] * inv) | ((uint)f2bf(a[7] * inv) << 16);
        ((uint4*)mean)[(size_t)node * 16 + cl] = o;
    }
}

// ---------------------------------------------------------------------------
// MFMA SAGE linear: out = mean @ Wl^T + root @ Wr^T + b.
// One wave per 16 rows x 128 cols; no LDS, no barriers.
// POOL variant fuses global_add_pool: rows grouped by (sorted) batch id,
// fp32 partial sums atomicAdd'ed straight into pooled[g][col].
// ---------------------------------------------------------------------------
template <bool POOL>
__global__ __launch_bounds__(256) void sage_gemm_mfma(const ushort* __restrict__ Amean,
                                                      const ushort* __restrict__ Aroot,
                                                      const ushort* __restrict__ WpL,
                                                      const float* __restrict__ bias,
                                                      const int* __restrict__ batch,
                                                      void* __restrict__ outv, int nwaves) {
    int w = blockIdx.x * 4 + (threadIdx.x >> 6);
    if (w >= nwaves) return;
    int lane = threadIdx.x & 63;
    int mrow = lane & 15;
    int quad = lane >> 4;
    int r0 = w * 16;

    f32x4 acc[8];
#pragma unroll
    for (int t = 0; t < 8; ++t) acc[t] = (f32x4){0.f, 0.f, 0.f, 0.f};

    const ushort* arow_m = Amean + ((size_t)(r0 + mrow)) * HID + quad * 8;
    const ushort* arow_r = Aroot + ((size_t)(r0 + mrow)) * HID + quad * 8;

#pragma unroll
    for (int half = 0; half < 2; ++half) {
        const ushort* arow = half ? arow_r : arow_m;
        const ushort* wb = WpL + (size_t)half * 16384 + (size_t)lane * 8;
#pragma unroll
        for (int c = 0; c < 4; ++c) {
            bf16x8 a = *(const bf16x8*)(arow + c * 32);
#pragma unroll
            for (int t = 0; t < 8; ++t) {
                bf16x8 b = *(const bf16x8*)(wb + (size_t)(t * 4 + c) * 512);
                acc[t] = __builtin_amdgcn_mfma_f32_16x16x32_bf16(a, b, acc[t], 0, 0, 0);
            }
        }
    }

    if (POOL) {
        float* pooled = (float*)outv;
        int rbase = r0 + quad * 4;
        int g0 = batch[rbase + 0];
        int g1 = batch[rbase + 1];
        int g2 = batch[rbase + 2];
        int g3 = batch[rbase + 3];
#pragma unroll
        for (int t = 0; t < 8; ++t) {
            int col = t * 16 + mrow;
            float bv = bias[col];
            float v0 = acc[t][0] + bv;
            float v1 = acc[t][1] + bv;
            float v2 = acc[t][2] + bv;
            float v3 = acc[t][3] + bv;
            int cg = g0;
            float s = v0;
            if (g1 == cg) s += v1; else { atomicAdd(&pooled[(size_t)cg * HID + col], s); cg = g1; s = v1; }
            if (g2 == cg) s += v2; else { atomicAdd(&pooled[(size_t)cg * HID + col], s); cg = g2; s = v2; }
            if (g3 == cg) s += v3; else { atomicAdd(&pooled[(size_t)cg * HID + col], s); cg = g3; s = v3; }
            atomicAdd(&pooled[(size_t)cg * HID + col], s);
        }
    } else {
        ushort* out = (ushort*)outv;
#pragma unroll
        for (int t = 0; t < 8; ++t) {
            int col = t * 16 + mrow;
            float bv = bias[col];
#pragma unroll
            for (int r = 0; r < 4; ++r) {
                int row = r0 + quad * 4 + r;
                out[(size_t)row * HID + col] = f2bf(acc[t][r] + bv);
            }
        }
    }
}

// ---------------------------------------------------------------------------
// Tail: lin1 + BN(eval) + relu + lin2. One block (128 thr) per graph.
// ---------------------------------------------------------------------------
__global__ __launch_bounds__(128) void tail_kernel(const float* __restrict__ pooled,
                                                   const float* __restrict__ lin1_w,
                                                   const float* __restrict__ lin1_b,
                                                   const float* __restrict__ lin2_w,
                                                   const float* __restrict__ lin2_b,
                                                   const float* __restrict__ gamma,
                                                   const float* __restrict__ beta,
                                                   const float* __restrict__ rmean,
                                                   const float* __restrict__ rvar,
                                                   float* __restrict__ out) {
    __shared__ float Wt[64 * 128];  // Wt[k][c ^ (k&31)] = lin1_w[c][k0+k]
    __shared__ float p[128];
    __shared__ float tbuf[128];
    int g = blockIdx.x;
    int c = threadIdx.x;
    p[c] = pooled[g * HID + c];
    float acc = lin1_b[c];
    int kk = c & 63;
    int chalf = c >> 6;
    for (int k0 = 0; k0 < 128; k0 += 64) {
        __syncthreads();
        for (int i = 0; i < 64; ++i) {
            int crow = i * 2 + chalf;
            float v = lin1_w[crow * HID + k0 + kk];
            Wt[kk * 128 + (crow ^ (kk & 31))] = v;
        }
        __syncthreads();
#pragma unroll
        for (int k = 0; k < 64; ++k) {
            acc += p[k0 + k] * Wt[k * 128 + (c ^ (k & 31))];
        }
    }
    float v = (acc - rmean[c]) * rsqrtf(rvar[c] + BN_EPS) * gamma[c] + beta[c];
    v = fmaxf(v, 0.f);
    tbuf[c] = v;
    __syncthreads();
    int j = c >> 6;
    int lane = c & 63;
    float partial = tbuf[lane] * lin2_w[j * HID + lane] +
                    tbuf[lane + 64] * lin2_w[j * HID + lane + 64];
    for (int off = 32; off > 0; off >>= 1) partial += __shfl_down(partial, off);
    if (lane == 0) out[g * 2 + j] = partial + lin2_b[j];
}

// ---------------------------------------------------------------------------
extern "C" void kernel_launch(void* const* d_in, const int* in_sizes, int n_in,
                              void* d_out, int out_size, void* d_ws, size_t ws_size,
                              hipStream_t stream) {
    const float* x = (const float*)d_in[0];
    const int* ei = (const int*)d_in[1];      // [2][E]
    const int* batch = (const int*)d_in[2];   // [N]
    const float* W1l = (const float*)d_in[3];
    const float* b1 = (const float*)d_in[4];
    const float* W1r = (const float*)d_in[5];
    const float* W2l = (const float*)d_in[6];
    const float* b2 = (const float*)d_in[7];
    const float* W2r = (const float*)d_in[8];
    const float* lin1_w = (const float*)d_in[9];
    const float* lin1_b = (const float*)d_in[10];
    const float* lin2_w = (const float*)d_in[11];
    const float* lin2_b = (const float*)d_in[12];
    const float* gamma = (const float*)d_in[13];
    const float* beta = (const float*)d_in[14];
    const float* rmean = (const float*)d_in[15];
    const float* rvar = (const float*)d_in[16];
    float* out = (float*)d_out;

    const int N = NN, E = NE;
    const int NWAVES = N / 16;  // 3125 exact

    // workspace carve (256B aligned)
    char* p = (char*)d_ws;
    auto carve = [&](size_t bytes) {
        void* r = (void*)p;
        p += (bytes + 255) & ~(size_t)255;
        return r;
    };
    int* deg = (int*)carve((size_t)N * 4);
    int* row_start = (int*)carve((size_t)N * 4);
    int* bsums = (int*)carve(1024 * 4);
    int* rank = (int*)carve((size_t)E * 4);
    int* srclist = (int*)carve((size_t)E * 4);
    ushort* xb = (ushort*)carve((size_t)N * HID * 2);
    ushort* meanb = (ushort*)carve((size_t)N * HID * 2);
    ushort* h1 = (ushort*)carve((size_t)N * HID * 2);
    float* pooled = (float*)carve((size_t)NG * HID * 4);
    ushort* Wp = (ushort*)carve(4 * 32 * 64 * 8 * 2);  // 128 KB

    hipMemsetAsync(deg, 0, (size_t)N * 4, stream);
    hipMemsetAsync(pooled, 0, (size_t)NG * HID * 4, stream);

    const int scanBlocks = (N + 255) / 256;  // 196
    hist_kernel<<<(E + 255) / 256, 256, 0, stream>>>(ei, E, deg, rank);
    scan1_kernel<<<scanBlocks, 256, 0, stream>>>(deg, row_start, bsums, N);
    scan2_kernel<<<1, 256, 0, stream>>>(bsums, scanBlocks);
    scan3_kernel<<<scanBlocks, 256, 0, stream>>>(row_start, bsums, N);
    fill_kernel<<<(E + 255) / 256, 256, 0, stream>>>(ei, E, row_start, rank, srclist);

    // feature convert + weight pack
    convert_bf16_kernel<<<(N * HID / 4 + 255) / 256, 256, 0, stream>>>(x, xb, N * HID / 4);
    wprep_kernel<<<128, 64, 0, stream>>>(W1l, W1r, W2l, W2r, Wp);

    // layer 1 (bf16 h1 out)
    aggregate_kernel<<<(N + 3) / 4, 256, 0, stream>>>(xb, row_start, deg, srclist, meanb, N);
    sage_gemm_mfma<false><<<(NWAVES + 3) / 4, 256, 0, stream>>>(meanb, xb, Wp, b1, nullptr, h1,
                                                                NWAVES);
    // layer 2 (fused global_add_pool)
    aggregate_kernel<<<(N + 3) / 4, 256, 0, stream>>>(h1, row_start, deg, srclist, meanb, N);
    sage_gemm_mfma<true><<<(NWAVES + 3) / 4, 256, 0, stream>>>(meanb, h1, Wp + 32768, b2, batch,
                                                               pooled, NWAVES);
    // tail
    tail_kernel<<<NG, 128, 0, stream>>>(pooled, lin1_w, lin1_b, lin2_w, lin2_b,
                                        gamma, beta, rmean, rvar, out);
}